// Round 8
// baseline (558.370 us; speedup 1.0000x reference)
//
#include <hip/hip_runtime.h>

typedef _Float16 f16x8 __attribute__((ext_vector_type(8)));
typedef float    f32x4 __attribute__((ext_vector_type(4)));

#define NSTEP 512
#define KS 104      // panel row stride in f16 (208 B, 16B-aligned; 4-way uniform banks = BW-optimal)

// 7-trans LSTM activation: gates (i,f,g,o) -> h, updates c.
// sigma(i)*tanh(g) = (eg-1)*r*Y, sigma(f) = r*X, r = rcp(X*Y),
// X=(eg+1)(1+ei), Y=1+ef; h = (ec-1)*rcp((ec+1)(1+eo)).
// exp args clamped <=21 (e^21=1.3e9; X*Y <= 2.2e27, no overflow; denoms >= 1, no denormal/NaN).
__device__ __forceinline__ float lstm_act_(float gi, float gf, float gg, float go, float& c) {
    float eg = __expf(fminf(gg + gg, 21.0f));
    float ei = __expf(fminf(-gi, 21.0f));
    float ef = __expf(fminf(-gf, 21.0f));
    float X  = (eg + 1.0f) * (1.0f + ei);
    float Y  = 1.0f + ef;
    float r  = __builtin_amdgcn_rcpf(X * Y);
    c = fmaf(r * X, c, (eg - 1.0f) * (r * Y));
    float ec = __expf(fminf(c + c, 21.0f));
    float eo = __expf(fminf(-go, 21.0f));
    float r2 = __builtin_amdgcn_rcpf((ec + 1.0f) * (1.0f + eo));
    return (ec - 1.0f) * r2;
}
__device__ __forceinline__ float sig_(float v) {
    return __builtin_amdgcn_rcpf(1.0f + __expf(-v));
}
__device__ __forceinline__ float tanh_(float v) {
    return 1.0f - 2.0f * __builtin_amdgcn_rcpf(__expf(v + v) + 1.0f);
}
// lane m <-> m^8 within each 16-lane row (proven exact in R7)
__device__ __forceinline__ float dpp_ror8(float v) {
    int i = __builtin_bit_cast(int, v);
    i = __builtin_amdgcn_mov_dpp(i, 0x128, 0xF, 0xF, false);   // row_ror:8
    return __builtin_bit_cast(float, i);
}

// 512 threads = 8 waves, grid 256 (1 block/CU), 16 batches = P(0-7) + Q(8-15).
// PING-PONG: per step, phase A = P-MFMA (half-width tiles) + Q-activations (from
// accQ computed last phase) ; phase B = Q-MFMA + P-activations. MFMA exec and
// ds_read latency hide under the trans burst of the other group. Panels are
// single-buffered (barrier separates each panel's write phase from read phase).
// Tiles: wave w owns tiles {2w,2w+1} (units 8w..8w+7), tile-row = usub*4+gate;
// B cols 0-7 = the phase's 8 batches (cols 8-15 junk, discarded). After combine,
// DPP row_ror:8 gives every lane exactly ONE activation: (myu, myrow).
__global__ __launch_bounds__(512, 2) void lstm_pp_kernel(
    const float* __restrict__ x,     const float* __restrict__ Wemb,
    const float* __restrict__ Wih1,  const float* __restrict__ Whh1,
    const float* __restrict__ b1,    const float* __restrict__ Wih2,
    const float* __restrict__ b2,    const float* __restrict__ Wout,
    const float* __restrict__ bout,  float* __restrict__ out)
{
    __shared__ __align__(16) _Float16 ActP[8][KS];      // 1664 B
    __shared__ __align__(16) _Float16 ActQ[8][KS];      // 1664 B
    __shared__ __align__(16) float h2tmp[16 * 64];      // 4096 B
    __shared__ __align__(16) float h2s[256 * 16];       // 16384 B
    __shared__ float part[32 * 16 * 2];                 // 4096 B

    const int t = threadIdx.x;
    const int l = t & 63;
    const int w = t >> 6;        // wave 0..7
    const int m = l & 15;        // tile A-row / B col / D col
    const int q = l >> 4;        // quad: D rows q*4+r
    const int b0 = blockIdx.x * 16;

    // ---- weight fragments (f16 hi + lo*2048) ------------------------------
    f16x8 wh[2][3], wl[2][3];
    #pragma unroll
    for (int tt = 0; tt < 2; ++tt) {
        const int n = (m & 3) * 64 + (2 * w + tt) * 4 + (m >> 2);  // gate-row
        #pragma unroll
        for (int kc = 0; kc < 3; ++kc) {
            #pragma unroll
            for (int jj = 0; jj < 8; ++jj) {
                int k = kc * 32 + (q << 3) + jj;
                float v = 0.0f;
                if (k < 20)       v = Wih1[n * 20 + k];
                else if (k < 84)  v = Whh1[n * 64 + (k - 20)];
                _Float16 hi = (_Float16)v;
                wh[tt][kc][jj] = hi;
                wl[tt][kc][jj] = (_Float16)((v - (float)hi) * 2048.0f);
            }
        }
    }
    f32x4 bias4[2];              // MFMA C-operand seed (kills per-phase init movs)
    #pragma unroll
    for (int tt = 0; tt < 2; ++tt)
        #pragma unroll
        for (int r = 0; r < 4; ++r)
            bias4[tt][r] = b1[r * 64 + (2 * w + tt) * 4 + q];
    const f32x4 z4 = {0.f, 0.f, 0.f, 0.f};

    // lane's activation identity (R7 mapping, proven)
    const int myu   = 8 * w + ((m >> 3) << 2) + q;
    const int myrow = m & 7;
    const int arow  = m & 7;     // frag-read row (valid addr even for m>=8)

    // ---- emb-writer role: t<160 -> (be=t&7, ee=t>>3) -----------------------
    const int be = t & 7;
    const int ee = t >> 3;
    const bool embp = (t < 160);
    const float* xrowP = x + (size_t)(b0 + be) * (2 * NSTEP);
    const float* xrowQ = x + (size_t)(b0 + 8 + be) * (2 * NSTEP);
    float we0 = 0.f, we1 = 0.f;
    if (embp) { we0 = Wemb[ee * 2]; we1 = Wemb[ee * 2 + 1]; }

    // ---- init panels: zero + emb(token 0) ----------------------------------
    for (int idx = t; idx < 8 * KS; idx += 512) {
        ((_Float16*)ActP)[idx] = (_Float16)0.0f;
        ((_Float16*)ActQ)[idx] = (_Float16)0.0f;
    }
    __syncthreads();
    if (embp) {
        ActP[be][ee] = (_Float16)fmaxf(xrowP[0] * we0 + xrowP[1] * we1, 0.0f);
        ActQ[be][ee] = (_Float16)fmaxf(xrowQ[0] * we0 + xrowQ[1] * we1, 0.0f);
    }
    __syncthreads();

    // ---- preloop: accQ = Q-gates(0) ----------------------------------------
    f32x4 a0q[2], a1q[2], a0p[2], a1p[2];
    {
        f16x8 bq[3] = {};
        if (m < 8) {
            #pragma unroll
            for (int kc = 0; kc < 3; ++kc)
                bq[kc] = *(const f16x8*)&ActQ[arow][kc * 32 + (q << 3)];
        }
        #pragma unroll
        for (int tt = 0; tt < 2; ++tt) {
            a0q[tt] = __builtin_amdgcn_mfma_f32_16x16x32_f16(wh[tt][0], bq[0], bias4[tt], 0, 0, 0);
            a1q[tt] = __builtin_amdgcn_mfma_f32_16x16x32_f16(wl[tt][0], bq[0], z4, 0, 0, 0);
            #pragma unroll
            for (int kc = 1; kc < 3; ++kc) {
                a0q[tt] = __builtin_amdgcn_mfma_f32_16x16x32_f16(wh[tt][kc], bq[kc], a0q[tt], 0, 0, 0);
                a1q[tt] = __builtin_amdgcn_mfma_f32_16x16x32_f16(wl[tt][kc], bq[kc], a1q[tt], 0, 0, 0);
            }
        }
    }
    __syncthreads();             // protect preloop ActQ reads from phase-A writes

    float cstP = 0.f, cstQ = 0.f;

    for (int i = 0; i < NSTEP; ++i) {
        const int ns = (i + 1 < NSTEP) ? i + 1 : NSTEP - 1;
        float xqa = 0.f, xqb = 0.f, xpa = 0.f, xpb = 0.f;
        if (embp) {              // both token prefetches issued early
            xqa = xrowQ[2 * ns]; xqb = xrowQ[2 * ns + 1];
            xpa = xrowP[2 * ns]; xpb = xrowP[2 * ns + 1];
        }

        // ================= phase A: P-MFMA + Q-acts =================
        {
            f16x8 bp[3] = {};
            if (m < 8) {
                #pragma unroll
                for (int kc = 0; kc < 3; ++kc)
                    bp[kc] = *(const f16x8*)&ActP[arow][kc * 32 + (q << 3)];
            }
            #pragma unroll
            for (int tt = 0; tt < 2; ++tt) {
                a0p[tt] = __builtin_amdgcn_mfma_f32_16x16x32_f16(wh[tt][0], bp[0], bias4[tt], 0, 0, 0);
                a1p[tt] = __builtin_amdgcn_mfma_f32_16x16x32_f16(wl[tt][0], bp[0], z4, 0, 0, 0);
                #pragma unroll
                for (int kc = 1; kc < 3; ++kc) {
                    a0p[tt] = __builtin_amdgcn_mfma_f32_16x16x32_f16(wh[tt][kc], bp[kc], a0p[tt], 0, 0, 0);
                    a1p[tt] = __builtin_amdgcn_mfma_f32_16x16x32_f16(wl[tt][kc], bp[kc], a1p[tt], 0, 0, 0);
                }
            }
            // Q activations (accQ holds Q-gates(i); MFMA exec hides under this)
            float G[4];
            #pragma unroll
            for (int r = 0; r < 4; ++r) {
                float g0 = fmaf(0x1p-11f, a1q[0][r], a0q[0][r]);
                float g1 = fmaf(0x1p-11f, a1q[1][r], a0q[1][r]);
                float gr = dpp_ror8(g1);
                G[r] = (m < 8) ? g0 : gr;
            }
            float hv = lstm_act_(G[0], G[1], G[2], G[3], cstQ);
            ActQ[myrow][20 + myu] = (_Float16)hv;
            if (embp)
                ActQ[be][ee] = (_Float16)fmaxf(xqa * we0 + xqb * we1, 0.0f);
        }
        __syncthreads();

        // ================= phase B: Q-MFMA + P-acts =================
        {
            f16x8 bq[3] = {};
            if (m < 8) {
                #pragma unroll
                for (int kc = 0; kc < 3; ++kc)
                    bq[kc] = *(const f16x8*)&ActQ[arow][kc * 32 + (q << 3)];
            }
            #pragma unroll
            for (int tt = 0; tt < 2; ++tt) {
                a0q[tt] = __builtin_amdgcn_mfma_f32_16x16x32_f16(wh[tt][0], bq[0], bias4[tt], 0, 0, 0);
                a1q[tt] = __builtin_amdgcn_mfma_f32_16x16x32_f16(wl[tt][0], bq[0], z4, 0, 0, 0);
                #pragma unroll
                for (int kc = 1; kc < 3; ++kc) {
                    a0q[tt] = __builtin_amdgcn_mfma_f32_16x16x32_f16(wh[tt][kc], bq[kc], a0q[tt], 0, 0, 0);
                    a1q[tt] = __builtin_amdgcn_mfma_f32_16x16x32_f16(wl[tt][kc], bq[kc], a1q[tt], 0, 0, 0);
                }
            }
            // P activations (a0p/a1p = P-gates(i))
            float G[4];
            #pragma unroll
            for (int r = 0; r < 4; ++r) {
                float g0 = fmaf(0x1p-11f, a1p[0][r], a0p[0][r]);
                float g1 = fmaf(0x1p-11f, a1p[1][r], a0p[1][r]);
                float gr = dpp_ror8(g1);
                G[r] = (m < 8) ? g0 : gr;
            }
            float hv = lstm_act_(G[0], G[1], G[2], G[3], cstP);
            ActP[myrow][20 + myu] = (_Float16)hv;
            if (embp)
                ActP[be][ee] = (_Float16)fmaxf(xpa * we0 + xpb * we1, 0.0f);
        }
        __syncthreads();
    }
    // final h: ActP rows = batches b0..b0+7, ActQ rows = b0+8..b0+15

    // ---- epilogue: h64 to fp32 ---------------------------------------------
    #pragma unroll
    for (int rep = 0; rep < 2; ++rep) {
        int idx = t + rep * 512;                 // 1024 values
        int b = idx >> 6, k = idx & 63;
        h2tmp[idx] = (b < 8) ? (float)ActP[b][20 + k] : (float)ActQ[b - 8][20 + k];
    }
    __syncthreads();

    // ---- LSTM2 (single step, h=c=0 -> f-gate irrelevant) -------------------
    {
        const int u = t & 255;
        const int bh0 = (t >> 8) * 8;
        float acci[8], accg[8], acco[8];
        float bi2 = b2[u], bg2 = b2[512 + u], bo2 = b2[768 + u];
        #pragma unroll
        for (int b = 0; b < 8; ++b) { acci[b] = bi2; accg[b] = bg2; acco[b] = bo2; }
        for (int k4 = 0; k4 < 64; k4 += 4) {
            float4 wi = *(const float4*)&Wih2[(size_t)u * 64 + k4];
            float4 wg = *(const float4*)&Wih2[(size_t)(512 + u) * 64 + k4];
            float4 wo = *(const float4*)&Wih2[(size_t)(768 + u) * 64 + k4];
            #pragma unroll
            for (int b = 0; b < 8; ++b) {
                float4 hb = *(const float4*)&h2tmp[(bh0 + b) * 64 + k4];
                acci[b] += wi.x * hb.x + wi.y * hb.y + wi.z * hb.z + wi.w * hb.w;
                accg[b] += wg.x * hb.x + wg.y * hb.y + wg.z * hb.z + wg.w * hb.w;
                acco[b] += wo.x * hb.x + wo.y * hb.y + wo.z * hb.z + wo.w * hb.w;
            }
        }
        #pragma unroll
        for (int b = 0; b < 8; ++b) {
            float c2 = sig_(acci[b]) * tanh_(accg[b]);
            h2s[u * 16 + bh0 + b] = sig_(acco[b]) * tanh_(c2);
        }
    }
    __syncthreads();

    // ---- output projection -------------------------------------------------
    {
        int b = t & 15, grp = t >> 4;            // 32 groups x 8 units
        float p0 = 0.f, p1 = 0.f;
        for (int uu = grp * 8; uu < grp * 8 + 8; ++uu) {
            float hvv = h2s[uu * 16 + b];
            p0 += hvv * Wout[uu];
            p1 += hvv * Wout[256 + uu];
        }
        part[(grp * 16 + b) * 2 + 0] = p0;
        part[(grp * 16 + b) * 2 + 1] = p1;
    }
    __syncthreads();
    if (t < 32) {
        int b = t >> 1, o = t & 1;
        float s0 = bout[o];
        for (int grp = 0; grp < 32; ++grp) s0 += part[(grp * 16 + b) * 2 + o];
        out[(size_t)(b0 + b) * 2 + o] = s0;
    }
}

extern "C" void kernel_launch(void* const* d_in, const int* in_sizes, int n_in,
                              void* d_out, int out_size, void* d_ws, size_t ws_size,
                              hipStream_t stream) {
    const float* x    = (const float*)d_in[0];
    const float* Wemb = (const float*)d_in[1];
    const float* Wih1 = (const float*)d_in[2];
    const float* Whh1 = (const float*)d_in[3];
    const float* b1   = (const float*)d_in[4];
    const float* Wih2 = (const float*)d_in[5];
    // d_in[6] = Whh2: unused (h=c=0 at LSTM2's single step)
    const float* b2   = (const float*)d_in[7];
    const float* Wout = (const float*)d_in[8];
    const float* bout = (const float*)d_in[9];
    float* out = (float*)d_out;

    lstm_pp_kernel<<<256, 512, 0, stream>>>(
        x, Wemb, Wih1, Whh1, b1, Wih2, b2, Wout, bout, out);
}

// Round 9
// 407.515 us; speedup vs baseline: 1.3702x; 1.3702x over previous
//
#include <hip/hip_runtime.h>

typedef _Float16 f16x8 __attribute__((ext_vector_type(8)));
typedef float    f32x4 __attribute__((ext_vector_type(4)));

#define NSTEP 512
#define BT 16       // batches per block = full MFMA tile width

// 7-trans LSTM activation (validated R8: absmax 6.1e-5 over 512 steps).
// sigma(i)*tanh(g) = (eg-1)*r*Y, sigma(f) = r*X, r = rcp(X*Y),
// X=(eg+1)(1+ei), Y=1+ef; h = (ec-1)*rcp((ec+1)(1+eo)).
__device__ __forceinline__ float lstm_act_(float gi, float gf, float gg, float go, float& c) {
    float eg = __expf(fminf(gg + gg, 21.0f));
    float ei = __expf(fminf(-gi, 21.0f));
    float ef = __expf(fminf(-gf, 21.0f));
    float X  = (eg + 1.0f) * (1.0f + ei);
    float Y  = 1.0f + ef;
    float r  = __builtin_amdgcn_rcpf(X * Y);
    c = fmaf(r * X, c, (eg - 1.0f) * (r * Y));
    float ec = __expf(fminf(c + c, 21.0f));
    float eo = __expf(fminf(-go, 21.0f));
    float r2 = __builtin_amdgcn_rcpf((ec + 1.0f) * (1.0f + eo));
    return (ec - 1.0f) * r2;
}
__device__ __forceinline__ float sig_(float v) {
    return __builtin_amdgcn_rcpf(1.0f + __expf(-v));
}
__device__ __forceinline__ float tanh_(float v) {
    return 1.0f - 2.0f * __builtin_amdgcn_rcpf(__expf(v + v) + 1.0f);
}

// 512 threads = 8 waves, grid 256 (1 block/CU), 16 batches/block. R6 skeleton:
// wave w owns tiles {2w,2w+1}; tile-row = usub*4+gate -> acc[tt][r] = gate r of
// unit u_tt = 8w+4tt+q, batch m; 2 activations per lane; 1 barrier/step.
// NEW vs R6:
//  - h-panel in FRAGMENT-MAJOR order P[kc][q][batch][jj]: B-frag ds_read_b128
//    address = base + laneid*16 -> lane-linear, conflict-free, minimal cycles.
//  - emb computed per-lane in registers from prefetched x (no LDS round-trip);
//    the emb-chunk MFMAs pre-seed a0/a1 BEFORE the barrier -> only 8 h-MFMAs
//    (2-deep chains) on the post-barrier critical path.
//  - 7-trans activation algebra (R8-validated).
// Precision: f16 2-pass weight split W = Whi + Wlo*2^-11 (Wlo prescaled x2048).
__global__ __launch_bounds__(512, 1) void lstm_mfma_kernel(
    const float* __restrict__ x,     const float* __restrict__ Wemb,
    const float* __restrict__ Wih1,  const float* __restrict__ Whh1,
    const float* __restrict__ b1,    const float* __restrict__ Wih2,
    const float* __restrict__ b2,    const float* __restrict__ Wout,
    const float* __restrict__ bout,  float* __restrict__ out)
{
    // [buf][kc][q][batch][jj] : (kc*64 + q*16 + m)*16B  -> lane-linear reads
    __shared__ __align__(16) _Float16 P[2][2][4][BT][8];   // 8192 B
    __shared__ __align__(16) float h2tmp[BT * 64];         // 4096 B
    __shared__ __align__(16) float h2s[256 * BT];          // 16384 B
    __shared__ float part[32 * BT * 2];                    // 4096 B

    const int t = threadIdx.x;
    const int l = t & 63;
    const int w = t >> 6;        // wave 0..7
    const int m = l & 15;        // tile A-row / B col (batch) / D col
    const int q = l >> 4;        // quad: D rows q*4+r ; B-frag k = kc*32+q*8+jj
    const int b0 = blockIdx.x * BT;

    // ---- weight fragments (f16 hi + lo*2048); chunk 0 = emb (k 0..19 + pad),
    //      chunks 1,2 = h (global h-k 0..31, 32..63) ---------------------------
    f16x8 wh[2][3], wl[2][3];
    #pragma unroll
    for (int tt = 0; tt < 2; ++tt) {
        const int n = (m & 3) * 64 + (2 * w + tt) * 4 + (m >> 2);  // gate-row
        #pragma unroll
        for (int c = 0; c < 3; ++c) {
            #pragma unroll
            for (int jj = 0; jj < 8; ++jj) {
                int kk = (q << 3) + jj;
                float v = 0.0f;
                if (c == 0) { if (kk < 20) v = Wih1[n * 20 + kk]; }
                else        { v = Whh1[n * 64 + (c - 1) * 32 + kk]; }
                _Float16 hi = (_Float16)v;
                wh[tt][c][jj] = hi;
                wl[tt][c][jj] = (_Float16)((v - (float)hi) * 2048.0f);
            }
        }
    }
    f32x4 bias4[2];              // MFMA C-seed for the emb chunk
    #pragma unroll
    for (int tt = 0; tt < 2; ++tt)
        #pragma unroll
        for (int r = 0; r < 4; ++r)
            bias4[tt][r] = b1[r * 64 + (2 * w + tt) * 4 + q];
    const f32x4 z4 = {0.f, 0.f, 0.f, 0.f};

    // ---- per-lane emb machinery: this lane's 8 We pairs (k = q*8+jj) --------
    float wea[8], web[8];
    #pragma unroll
    for (int jj = 0; jj < 8; ++jj) {
        int k = (q << 3) + jj;
        wea[jj] = (k < 20) ? Wemb[2 * k]     : 0.0f;
        web[jj] = (k < 20) ? Wemb[2 * k + 1] : 0.0f;
    }
    const float* xrow = x + (size_t)(b0 + m) * (2 * NSTEP);

    // ---- zero buf 0 (h(-1) = 0); buf 1 gets fully written in iter 0 ---------
    for (int idx = t; idx < 2 * 4 * BT * 8; idx += 512)
        ((_Float16*)P[0])[idx] = (_Float16)0.0f;

    // ---- pre-seed a0/a1 with bias + emb(token 0) ----------------------------
    f32x4 a0[2], a1[2];
    {
        float x0 = xrow[0], x1 = xrow[1];
        f16x8 ef;
        #pragma unroll
        for (int jj = 0; jj < 8; ++jj)
            ef[jj] = (_Float16)fmaxf(fmaf(x0, wea[jj], x1 * web[jj]), 0.0f);
        #pragma unroll
        for (int tt = 0; tt < 2; ++tt) {
            a0[tt] = __builtin_amdgcn_mfma_f32_16x16x32_f16(wh[tt][0], ef, bias4[tt], 0, 0, 0);
            a1[tt] = __builtin_amdgcn_mfma_f32_16x16x32_f16(wl[tt][0], ef, z4, 0, 0, 0);
        }
    }
    float xp0 = xrow[2], xp1 = xrow[3];      // token 1 prefetch
    __syncthreads();

    // ---- main recurrence ----------------------------------------------------
    float cst[2] = {0.f, 0.f};
    int cur = 0;

    for (int i = 0; i < NSTEP; ++i) {
        // h(i-1) B-frags: lane-linear, conflict-free
        const _Float16* base = &P[cur][0][q][m][0];
        f16x8 f0 = *(const f16x8*)(base);
        f16x8 f1 = *(const f16x8*)(base + 4 * BT * 8);   // kc=1 plane

        #pragma unroll
        for (int tt = 0; tt < 2; ++tt) {
            a0[tt] = __builtin_amdgcn_mfma_f32_16x16x32_f16(wh[tt][1], f0, a0[tt], 0, 0, 0);
            a1[tt] = __builtin_amdgcn_mfma_f32_16x16x32_f16(wl[tt][1], f0, a1[tt], 0, 0, 0);
            a0[tt] = __builtin_amdgcn_mfma_f32_16x16x32_f16(wh[tt][2], f1, a0[tt], 0, 0, 0);
            a1[tt] = __builtin_amdgcn_mfma_f32_16x16x32_f16(wl[tt][2], f1, a1[tt], 0, 0, 0);
        }

        // activations: 2 per lane (unit u_tt = 8w+4tt+q, batch m)
        const int nxt = cur ^ 1;
        #pragma unroll
        for (int tt = 0; tt < 2; ++tt) {
            float gi = fmaf(0x1p-11f, a1[tt][0], a0[tt][0]);
            float gf = fmaf(0x1p-11f, a1[tt][1], a0[tt][1]);
            float gg = fmaf(0x1p-11f, a1[tt][2], a0[tt][2]);
            float go = fmaf(0x1p-11f, a1[tt][3], a0[tt][3]);
            float hv = lstm_act_(gi, gf, gg, go, cst[tt]);
            int u = 8 * w + 4 * tt + q;
            P[nxt][u >> 5][(u >> 3) & 3][m][u & 7] = (_Float16)hv;
        }

        // pre-seed a0/a1 with bias + emb(token i+1)  (barrier-independent)
        {
            f16x8 ef;
            #pragma unroll
            for (int jj = 0; jj < 8; ++jj)
                ef[jj] = (_Float16)fmaxf(fmaf(xp0, wea[jj], xp1 * web[jj]), 0.0f);
            #pragma unroll
            for (int tt = 0; tt < 2; ++tt) {
                a0[tt] = __builtin_amdgcn_mfma_f32_16x16x32_f16(wh[tt][0], ef, bias4[tt], 0, 0, 0);
                a1[tt] = __builtin_amdgcn_mfma_f32_16x16x32_f16(wl[tt][0], ef, z4, 0, 0, 0);
            }
        }
        // prefetch token i+2 (clamped)
        int ns = (i + 2 < NSTEP) ? i + 2 : NSTEP - 1;
        xp0 = xrow[2 * ns]; xp1 = xrow[2 * ns + 1];

        __syncthreads();
        cur = nxt;
    }
    // final h(511) in P[cur]

    // ---- epilogue: h64 to fp32 ---------------------------------------------
    #pragma unroll
    for (int rep = 0; rep < 2; ++rep) {
        int idx = t + rep * 512;                 // 1024 values
        int b = idx >> 6, k = idx & 63;
        h2tmp[idx] = (float)P[cur][k >> 5][(k >> 3) & 3][b][k & 7];
    }
    __syncthreads();

    // ---- LSTM2 (single step, h=c=0 -> f-gate irrelevant) -------------------
    {
        const int u = t & 255;
        const int bh0 = (t >> 8) * 8;
        float acci[8], accg[8], acco[8];
        float bi2 = b2[u], bg2 = b2[512 + u], bo2 = b2[768 + u];
        #pragma unroll
        for (int b = 0; b < 8; ++b) { acci[b] = bi2; accg[b] = bg2; acco[b] = bo2; }
        for (int k4 = 0; k4 < 64; k4 += 4) {
            float4 wi = *(const float4*)&Wih2[(size_t)u * 64 + k4];
            float4 wg = *(const float4*)&Wih2[(size_t)(512 + u) * 64 + k4];
            float4 wo = *(const float4*)&Wih2[(size_t)(768 + u) * 64 + k4];
            #pragma unroll
            for (int b = 0; b < 8; ++b) {
                float4 hb = *(const float4*)&h2tmp[(bh0 + b) * 64 + k4];
                acci[b] += wi.x * hb.x + wi.y * hb.y + wi.z * hb.z + wi.w * hb.w;
                accg[b] += wg.x * hb.x + wg.y * hb.y + wg.z * hb.z + wg.w * hb.w;
                acco[b] += wo.x * hb.x + wo.y * hb.y + wo.z * hb.z + wo.w * hb.w;
            }
        }
        #pragma unroll
        for (int b = 0; b < 8; ++b) {
            float c2 = sig_(acci[b]) * tanh_(accg[b]);
            h2s[u * BT + bh0 + b] = sig_(acco[b]) * tanh_(c2);
        }
    }
    __syncthreads();

    // ---- output projection -------------------------------------------------
    {
        int b = t & 15, grp = t >> 4;            // 32 groups x 8 units
        float p0 = 0.f, p1 = 0.f;
        for (int uu = grp * 8; uu < grp * 8 + 8; ++uu) {
            float hvv = h2s[uu * BT + b];
            p0 += hvv * Wout[uu];
            p1 += hvv * Wout[256 + uu];
        }
        part[(grp * BT + b) * 2 + 0] = p0;
        part[(grp * BT + b) * 2 + 1] = p1;
    }
    __syncthreads();
    if (t < 32) {
        int b = t >> 1, o = t & 1;
        float s0 = bout[o];
        for (int grp = 0; grp < 32; ++grp) s0 += part[(grp * BT + b) * 2 + o];
        out[(size_t)(b0 + b) * 2 + o] = s0;
    }
}

extern "C" void kernel_launch(void* const* d_in, const int* in_sizes, int n_in,
                              void* d_out, int out_size, void* d_ws, size_t ws_size,
                              hipStream_t stream) {
    const float* x    = (const float*)d_in[0];
    const float* Wemb = (const float*)d_in[1];
    const float* Wih1 = (const float*)d_in[2];
    const float* Whh1 = (const float*)d_in[3];
    const float* b1   = (const float*)d_in[4];
    const float* Wih2 = (const float*)d_in[5];
    // d_in[6] = Whh2: unused (h=c=0 at LSTM2's single step)
    const float* b2   = (const float*)d_in[7];
    const float* Wout = (const float*)d_in[8];
    const float* bout = (const float*)d_in[9];
    float* out = (float*)d_out;

    lstm_mfma_kernel<<<256, 512, 0, stream>>>(
        x, Wemb, Wih1, Whh1, b1, Wih2, b2, Wout, bout, out);
}